// Round 2
// baseline (923.362 us; speedup 1.0000x reference)
//
#include <hip/hip_runtime.h>

typedef __attribute__((ext_vector_type(8))) short s16x8;
typedef __attribute__((ext_vector_type(4))) float f32x4;

#define WS_SEG 67108864  // 64 MiB per region: [t/O][Q][K][Vt]

static __device__ __forceinline__ unsigned short f2bf(float f) {
    unsigned int u = __builtin_bit_cast(unsigned int, f);
    u = (u + 0x7FFFu + ((u >> 16) & 1u)) >> 16;   // RNE
    return (unsigned short)u;
}
static __device__ __forceinline__ unsigned int pack2(float a, float b) {
    return (unsigned int)f2bf(a) | ((unsigned int)f2bf(b) << 16);
}
static __device__ __forceinline__ s16x8 u4cast(uint4 u) {
    return __builtin_bit_cast(s16x8, u);
}

// ---------------------------------------------------------------------------
// Kernel A: convert w_in (f32, 196608) -> bf16 into scratch (d_out tail)
// ---------------------------------------------------------------------------
__global__ __launch_bounds__(256) void convw(const float* __restrict__ wi,
                                             unsigned short* __restrict__ wb) {
    int i = (blockIdx.x * 256 + threadIdx.x) * 4;
    float4 v = *reinterpret_cast<const float4*>(wi + i);
    uint2 o = { pack2(v.x, v.y), pack2(v.z, v.w) };
    *reinterpret_cast<uint2*>(wb + i) = o;
}

// ---------------------------------------------------------------------------
// Kernel 0: patch gather  x[2,256,256,256] f32 -> t bf16 [131072][256]
// ---------------------------------------------------------------------------
__global__ __launch_bounds__(256) void gather_bf16(const float* __restrict__ x,
                                                   unsigned short* __restrict__ t) {
    int q = (blockIdx.x * 256 + threadIdx.x) * 4;
    int e = q & 255, c = (q >> 8) & 255, n = q >> 16;
    int b = n >> 8, p = n & 255;
    int xi = ((b * 256 + c) * 256 + (p >> 4) * 16 + (e >> 4)) * 256 + (p & 15) * 16 + (e & 15);
    float4 v = *reinterpret_cast<const float4*>(x + xi);
    uint2 o = { pack2(v.x, v.y), pack2(v.z, v.w) };
    *reinterpret_cast<uint2*>(t + q) = o;
}

// ---------------------------------------------------------------------------
// Direct-fragment GEMM (no LDS, no barriers):
//   C[M=131072][N] = A(bf16,[M][256]) @ W([N][256])^T + bias
// Block = 64 M-rows, 4 waves.
// MODE 0: N=768, BN=384 (grid.y=2), wave covers 64x96; W pre-converted bf16.
//         scatter to Q/K [nh][c][64], Vt [nh][64][c]  (bf16)
// MODE 1: N=256 single pass, wave covers 64x64; W f32 converted on the fly.
//         scatter to out f32 [b][c][p][e]
// ---------------------------------------------------------------------------
template<int MODE>
__global__ __launch_bounds__(256, 3) void gemm_direct(
    const unsigned short* __restrict__ A,
    const unsigned short* __restrict__ Wb,   // bf16 weights (MODE 0)
    const float* __restrict__ Wf,            // f32 weights (MODE 1)
    const float* __restrict__ bias,
    unsigned short* __restrict__ Qo, unsigned short* __restrict__ Ko,
    unsigned short* __restrict__ Vt, float* __restrict__ Out)
{
    constexpr int FN = (MODE == 0) ? 6 : 4;
    const int t = threadIdx.x, w = t >> 6, lane = t & 63;
    const int lr = lane & 15, lk = lane >> 4;
    const int bm = blockIdx.x, bn = blockIdx.y;
    const int mbase = bm * 64;
    const int nbase = (MODE == 0) ? (bn * 384 + w * 96) : (w * 64);

    f32x4 acc[4][FN] = {};

    #pragma unroll
    for (int kc = 0; kc < 8; ++kc) {
        s16x8 af[4];
        #pragma unroll
        for (int fm = 0; fm < 4; ++fm)
            af[fm] = *reinterpret_cast<const s16x8*>(
                A + (mbase + fm * 16 + lr) * 256 + kc * 32 + lk * 8);
        s16x8 bf[FN];
        #pragma unroll
        for (int fn = 0; fn < FN; ++fn) {
            if (MODE == 0) {
                bf[fn] = *reinterpret_cast<const s16x8*>(
                    Wb + (nbase + fn * 16 + lr) * 256 + kc * 32 + lk * 8);
            } else {
                const float* wp = Wf + (nbase + fn * 16 + lr) * 256 + kc * 32 + lk * 8;
                float4 x0 = *reinterpret_cast<const float4*>(wp);
                float4 x1 = *reinterpret_cast<const float4*>(wp + 4);
                uint4 u = { pack2(x0.x, x0.y), pack2(x0.z, x0.w),
                            pack2(x1.x, x1.y), pack2(x1.z, x1.w) };
                bf[fn] = u4cast(u);
            }
        }
        #pragma unroll
        for (int fm = 0; fm < 4; ++fm)
            #pragma unroll
            for (int fn = 0; fn < FN; ++fn)
                acc[fm][fn] = __builtin_amdgcn_mfma_f32_16x16x32_bf16(af[fm], bf[fn], acc[fm][fn], 0, 0, 0);
    }

    #pragma unroll
    for (int fn = 0; fn < FN; ++fn) {
        const int colg = nbase + fn * 16 + lr;
        const float bv = bias[colg];
        #pragma unroll
        for (int fm = 0; fm < 4; ++fm) {
            #pragma unroll
            for (int j = 0; j < 4; ++j) {
                const int rg = mbase + fm * 16 + lk * 4 + j;   // row = n*256 + c
                const float val = acc[fm][fn][j] + bv;
                if (MODE == 0) {
                    const int n = rg >> 8, c = rg & 255;
                    const int which = colg >> 8, rem = colg & 255;
                    const int h = rem >> 6, d = rem & 63;
                    if (which == 0)      Qo[((n * 4 + h) * 256 + c) * 64 + d] = f2bf(val);
                    else if (which == 1) Ko[((n * 4 + h) * 256 + c) * 64 + d] = f2bf(val);
                    else                 Vt[((n * 4 + h) * 64 + d) * 256 + c] = f2bf(val);
                } else {
                    const int n = rg >> 8, c = rg & 255;
                    const int b = n >> 8, p = n & 255;
                    Out[((b * 256 + c) * 256 + p) * 256 + colg] = val;
                }
            }
        }
    }
}

// ---------------------------------------------------------------------------
// Kernel 2: attention v2. One block per (n,h); 4 independent waves.
// S^T = mfma(K,Q): each lane holds all 256 scores for its q -> in-register
// softmax (2 shfl_xor). P packed to bf16 with permuted-key bijection so PV
// needs no shuffles; V^T A-frags honor the same permutation (2x8B loads).
// Only K staged in LDS (XOR-swizzled). O via per-wave LDS transpose.
// ---------------------------------------------------------------------------
__global__ __launch_bounds__(256, 4) void attn2(
    const unsigned short* __restrict__ Q,
    const unsigned short* __restrict__ K,
    const unsigned short* __restrict__ Vt,
    unsigned short* __restrict__ O)
{
    __shared__ __align__(16) unsigned short Ks[16384];      // 32 KB swizzled [key][d]
    __shared__ __align__(16) unsigned short Otr[4][1024];   // 2 KB per wave

    const int nh = blockIdx.x;
    const int n = nh >> 2, h = nh & 3;
    const int t = threadIdx.x, w = t >> 6, lane = t & 63;
    const int lr = lane & 15, lk = lane >> 4;

    const unsigned short* Qg = Q + nh * 16384;
    const unsigned short* Kg = K + nh * 16384;
    const unsigned short* Vg = Vt + nh * 16384;

    // ---- stage K (32 KB), XOR swizzle: phys_col_byte = col ^ ((row&7)<<4)
    char* KsB = (char*)Ks;
    #pragma unroll
    for (int i = 0; i < 8; ++i) {
        int lin = i * 256 + t;            // 16B-unit index 0..2047
        int row = lin >> 3;
        int cb = (lin & 7) * 16;
        uint4 val = *reinterpret_cast<const uint4*>(Kg + row * 64 + (cb >> 1));
        *reinterpret_cast<uint4*>(KsB + row * 128 + (cb ^ ((row & 7) << 4))) = val;
    }
    __syncthreads();

    const float sc = 0.125f * 1.44269504f;   // HD^-0.5 * log2(e)

    for (int it = 0; it < 4; ++it) {
        const int qt = w * 4 + it;

        s16x8 bq0 = *reinterpret_cast<const s16x8*>(Qg + (qt * 16 + lr) * 64 + lk * 8);
        s16x8 bq1 = *reinterpret_cast<const s16x8*>(Qg + (qt * 16 + lr) * 64 + 32 + lk * 8);

        // ---- S^T: lane holds S[key = 16*kt + 4*lk + j][q = qt*16+lr]
        f32x4 s[16];
        #pragma unroll
        for (int kt = 0; kt < 16; ++kt) {
            const int rb = (kt * 16 + lr) * 128;
            const int swz = (lr & 7) << 4;
            s16x8 a0 = *reinterpret_cast<const s16x8*>(KsB + rb + ((lk * 16) ^ swz));
            s16x8 a1 = *reinterpret_cast<const s16x8*>(KsB + rb + ((64 + lk * 16) ^ swz));
            f32x4 z = { 0.f, 0.f, 0.f, 0.f };
            z = __builtin_amdgcn_mfma_f32_16x16x32_bf16(a0, bq0, z, 0, 0, 0);
            z = __builtin_amdgcn_mfma_f32_16x16x32_bf16(a1, bq1, z, 0, 0, 0);
            s[kt] = z;
        }

        // ---- in-register softmax over 256 keys (64 here + cross-lk shfl)
        float m = s[0][0];
        #pragma unroll
        for (int kt = 0; kt < 16; ++kt)
            #pragma unroll
            for (int j = 0; j < 4; ++j) m = fmaxf(m, s[kt][j]);
        m = fmaxf(m, __shfl_xor(m, 16));
        m = fmaxf(m, __shfl_xor(m, 32));
        float l = 0.f;
        #pragma unroll
        for (int kt = 0; kt < 16; ++kt)
            #pragma unroll
            for (int j = 0; j < 4; ++j) {
                float p = exp2f((s[kt][j] - m) * sc);
                s[kt][j] = p;
                l += p;
            }
        l += __shfl_xor(l, 16);
        l += __shfl_xor(l, 32);

        // ---- O^T = V^T @ P^T with permuted key bijection (no shuffles)
        f32x4 oacc[4] = {};
        #pragma unroll
        for (int kb = 0; kb < 8; ++kb) {
            uint4 pf = { pack2(s[2 * kb][0],     s[2 * kb][1]),
                         pack2(s[2 * kb][2],     s[2 * kb][3]),
                         pack2(s[2 * kb + 1][0], s[2 * kb + 1][1]),
                         pack2(s[2 * kb + 1][2], s[2 * kb + 1][3]) };
            s16x8 bp = u4cast(pf);
            #pragma unroll
            for (int dt = 0; dt < 4; ++dt) {
                const unsigned short* vp = Vg + (dt * 16 + lr) * 256 + kb * 32 + lk * 4;
                uint2 v0 = *reinterpret_cast<const uint2*>(vp);
                uint2 v1 = *reinterpret_cast<const uint2*>(vp + 16);
                uint4 uu = { v0.x, v0.y, v1.x, v1.y };
                oacc[dt] = __builtin_amdgcn_mfma_f32_16x16x32_bf16(u4cast(uu), bp, oacc[dt], 0, 0, 0);
            }
        }

        // ---- normalize, transpose via per-wave LDS, 16B coalesced store
        const float rl = 1.0f / l;
        char* ob = (char*)&Otr[w][0];
        #pragma unroll
        for (int dt = 0; dt < 4; ++dt) {
            unsigned int w0 = pack2(oacc[dt][0] * rl, oacc[dt][1] * rl);
            unsigned int w1 = pack2(oacc[dt][2] * rl, oacc[dt][3] * rl);
            int cb0 = dt * 32 + lk * 8;                    // byte col of d*2
            int swz = (lr & 7) << 4;
            *reinterpret_cast<unsigned int*>(ob + lr * 128 + (cb0 ^ swz)) = w0;
            *reinterpret_cast<unsigned int*>(ob + lr * 128 + ((cb0 + 4) ^ swz)) = w1;
        }
        #pragma unroll
        for (int p = 0; p < 2; ++p) {
            int q = lane >> 2;
            int cb = (lane & 3) * 32 + p * 16;
            uint4 vv = *reinterpret_cast<const uint4*>(ob + q * 128 + (cb ^ ((q & 7) << 4)));
            *reinterpret_cast<uint4*>(O + (n * 256 + qt * 16 + q) * 256 + h * 64 + (cb >> 1)) = vv;
        }
    }
}

// ---------------------------------------------------------------------------
extern "C" void kernel_launch(void* const* d_in, const int* in_sizes, int n_in,
                              void* d_out, int out_size, void* d_ws, size_t ws_size,
                              hipStream_t stream) {
    const float* x     = (const float*)d_in[0];
    const float* w_in  = (const float*)d_in[1];
    const float* b_in  = (const float*)d_in[2];
    const float* w_out = (const float*)d_in[3];
    const float* b_out = (const float*)d_in[4];
    float* out = (float*)d_out;

    char* ws = (char*)d_ws;
    unsigned short* tO = (unsigned short*)(ws);               // t, later O (aliased)
    unsigned short* Qw = (unsigned short*)(ws + (size_t)WS_SEG);
    unsigned short* Kw = (unsigned short*)(ws + (size_t)2 * WS_SEG);
    unsigned short* Vw = (unsigned short*)(ws + (size_t)3 * WS_SEG);

    // bf16 w_in lives in the tail of d_out (overwritten later by gemm2)
    unsigned short* WbIn = (unsigned short*)d_out + ((size_t)out_size * 2 - 196608);

    convw<<<192, 256, 0, stream>>>(w_in, WbIn);
    gather_bf16<<<32768, 256, 0, stream>>>(x, tO);

    dim3 g1(2048, 2);   // M=131072/64, N=768/384
    gemm_direct<0><<<g1, 256, 0, stream>>>(tO, WbIn, nullptr, b_in, Qw, Kw, Vw, nullptr);

    attn2<<<2048, 256, 0, stream>>>(Qw, Kw, Vw, tO);          // O overwrites t

    dim3 g3(2048, 1);   // N=256
    gemm_direct<1><<<g3, 256, 0, stream>>>(tO, nullptr, w_out, b_out, nullptr, nullptr, nullptr, out);
}

// Round 3
// 356.662 us; speedup vs baseline: 2.5889x; 2.5889x over previous
//
#include <hip/hip_runtime.h>

typedef __attribute__((ext_vector_type(8))) short s16x8;
typedef __attribute__((ext_vector_type(4))) float f32x4;

#define WS_SEG 67108864ULL  // 64 MiB regions: [t/O][Q][K][Vt]

static __device__ __forceinline__ unsigned short f2bf(float f) {
    unsigned int u = __builtin_bit_cast(unsigned int, f);
    u = (u + 0x7FFFu + ((u >> 16) & 1u)) >> 16;   // RNE
    return (unsigned short)u;
}
static __device__ __forceinline__ unsigned int pack2(float a, float b) {
    return (unsigned int)f2bf(a) | ((unsigned int)f2bf(b) << 16);
}
static __device__ __forceinline__ s16x8 u4cast(uint4 u) {
    return __builtin_bit_cast(s16x8, u);
}
// async global->LDS, 16B per lane; lds dest = wave-uniform base + lane*16
static __device__ __forceinline__ void gl_lds16(const void* g, void* l) {
    __builtin_amdgcn_global_load_lds(
        (const __attribute__((address_space(1))) unsigned int*)g,
        (__attribute__((address_space(3))) unsigned int*)l, 16, 0, 0);
}

// ---------------------------------------------------------------------------
// Weight convert f32 -> bf16, pre-swizzled: within each 128B k-chunk of a row,
// phys_cb = cb ^ ((row&7)<<4). Used for w_in (768x256) and w_out (256x256).
// ---------------------------------------------------------------------------
__global__ __launch_bounds__(256) void convw_swz(const float* __restrict__ wi,
                                                 unsigned short* __restrict__ wb) {
    int i = (blockIdx.x * 256 + threadIdx.x) * 4;   // element idx
    float4 v = *reinterpret_cast<const float4*>(wi + i);
    int bb = i * 2;                                  // byte addr in bf16 matrix
    int row = i >> 8;
    int dst = (bb & ~127) | ((bb & 127) ^ ((row & 7) << 4));
    uint2 o = { pack2(v.x, v.y), pack2(v.z, v.w) };
    *reinterpret_cast<uint2*>((char*)wb + dst) = o;
}

// ---------------------------------------------------------------------------
// Patch gather x[2,256,256,256] f32 -> t bf16 [131072][256], pre-swizzled.
// ---------------------------------------------------------------------------
__global__ __launch_bounds__(256) void gather_swz(const float* __restrict__ x,
                                                  unsigned short* __restrict__ t) {
    int q = (blockIdx.x * 256 + threadIdx.x) * 4;
    int e = q & 255, c = (q >> 8) & 255, n = q >> 16;
    int b = n >> 8, p = n & 255;
    int xi = ((b * 256 + c) * 256 + (p >> 4) * 16 + (e >> 4)) * 256 + (p & 15) * 16 + (e & 15);
    float4 v = *reinterpret_cast<const float4*>(x + xi);
    int bb = q * 2;
    int row = q >> 8;
    int dst = (bb & ~127) | ((bb & 127) ^ ((row & 7) << 4));
    uint2 o = { pack2(v.x, v.y), pack2(v.z, v.w) };
    *reinterpret_cast<uint2*>((char*)t + dst) = o;
}

// ---------------------------------------------------------------------------
// GEMM: C[M][N] = A @ W^T + bias. A,W bf16 [*][256] PRE-SWIZZLED.
// 128x128 tile, BK=64, 4 waves (2x2 -> 64x64 each), global_load_lds staging.
// MODE 0: N=768 (grid.x=6). Epilogue: LDS transpose -> coalesced stores to
//         Q/K [nh][c][64] and Vt [nh][64][c] (all LINEAR bf16).
// MODE 1: N=256 (grid.x=2). Epilogue: direct f32 stores to out [b][c][p][e].
// ---------------------------------------------------------------------------
template<int MODE>
__global__ __launch_bounds__(256) void gemm3(
    const unsigned short* __restrict__ A,
    const unsigned short* __restrict__ Wb,
    const float* __restrict__ bias,
    unsigned short* __restrict__ Qo, unsigned short* __restrict__ Ko,
    unsigned short* __restrict__ Vt, float* __restrict__ Out)
{
    __shared__ __align__(16) char smem[32768];
    char* AsB = smem;            // 16KB: [128 rows][128B], swizzled
    char* BsB = smem + 16384;

    const int t = threadIdx.x, w = t >> 6, lane = t & 63;
    const int lr = lane & 15, lk = lane >> 4;
    const int wm = w >> 1, wn = w & 1;
    const int bn = blockIdx.x, bm = blockIdx.y;

    f32x4 acc[4][4] = {};

    const char* Ag = (const char*)A + (size_t)bm * 65536;   // 128 rows * 512B
    const char* Bg = (const char*)Wb + (size_t)bn * 65536;

    for (int kk = 0; kk < 4; ++kk) {
        #pragma unroll
        for (int i = 0; i < 4; ++i) {
            int u = (i * 4 + w) * 64 + lane;          // 0..1023 (16B units)
            int row = u >> 3, cb = (u & 7) * 16;
            gl_lds16(Ag + row * 512 + kk * 128 + cb, AsB + (i * 4 + w) * 1024);
            gl_lds16(Bg + row * 512 + kk * 128 + cb, BsB + (i * 4 + w) * 1024);
        }
        __syncthreads();
        #pragma unroll
        for (int kc = 0; kc < 2; ++kc) {
            s16x8 af[4], bf[4];
            #pragma unroll
            for (int fm = 0; fm < 4; ++fm) {
                int r = wm * 64 + fm * 16 + lr;
                af[fm] = *reinterpret_cast<const s16x8*>(
                    AsB + r * 128 + ((kc * 64 + lk * 16) ^ ((r & 7) << 4)));
            }
            #pragma unroll
            for (int fn = 0; fn < 4; ++fn) {
                int cc = wn * 64 + fn * 16 + lr;
                bf[fn] = *reinterpret_cast<const s16x8*>(
                    BsB + cc * 128 + ((kc * 64 + lk * 16) ^ ((cc & 7) << 4)));
            }
            #pragma unroll
            for (int fm = 0; fm < 4; ++fm)
                #pragma unroll
                for (int fn = 0; fn < 4; ++fn)
                    acc[fm][fn] = __builtin_amdgcn_mfma_f32_16x16x32_bf16(af[fm], bf[fn], acc[fm][fn], 0, 0, 0);
        }
        __syncthreads();
    }

    if (MODE == 1) {
        #pragma unroll
        for (int fn = 0; fn < 4; ++fn) {
            int colg = bn * 128 + wn * 64 + fn * 16 + lr;
            float bv = bias[colg];
            #pragma unroll
            for (int fm = 0; fm < 4; ++fm)
                #pragma unroll
                for (int j = 0; j < 4; ++j) {
                    int rg = bm * 128 + wm * 64 + fm * 16 + lk * 4 + j;
                    int n = rg >> 8, c = rg & 255;
                    int b = n >> 8, p = n & 255;
                    Out[(((b * 256 + c) * 256 + p) << 8) + colg] = acc[fm][fn][j] + bv;
                }
        }
        return;
    }

    // ---- MODE 0 epilogue: transpose through LDS (smem reused; k-loop ended
    // with a barrier so As/Bs are dead).
    unsigned short* T = (unsigned short*)smem;
    const int X = bn >> 1;            // 0=Q, 1=K, 2=V
    const int h0 = (bn & 1) * 2;
    const int n = bm >> 1;

    #pragma unroll
    for (int fn = 0; fn < 4; ++fn) {
        int col_local = wn * 64 + fn * 16 + lr;       // 0..127
        float bv = bias[bn * 128 + col_local];
        #pragma unroll
        for (int fm = 0; fm < 4; ++fm)
            #pragma unroll
            for (int j = 0; j < 4; ++j) {
                int c_local = wm * 64 + fm * 16 + lk * 4 + j;   // 0..127
                unsigned short hv = f2bf(acc[fm][fn][j] + bv);
                if (X < 2) {
                    // T[c_local][col_local]: rows of 256B
                    *reinterpret_cast<unsigned short*>(
                        (char*)T + c_local * 256 + col_local * 2) = hv;
                } else {
                    int hl = col_local >> 6, d = col_local & 63;
                    *reinterpret_cast<unsigned short*>(
                        (char*)T + hl * 16384 + d * 256 + ((c_local * 2) ^ ((d & 7) << 4))) = hv;
                }
            }
    }
    __syncthreads();

    if (X < 2) {
        unsigned short* base = (X == 0) ? Qo : Ko;
        #pragma unroll
        for (int i = 0; i < 8; ++i) {
            int u = i * 256 + t;                 // 16B units, 2048 total
            int c_local = u >> 4;
            int cbyte = (u & 15) * 16;           // 0..255 across 2 heads
            int h = h0 + (cbyte >> 7);
            int db = cbyte & 127;
            uint4 vv = *reinterpret_cast<const uint4*>((char*)T + u * 16);
            int c = (bm & 1) * 128 + c_local;
            *reinterpret_cast<uint4*>(
                (char*)base + (size_t)((n * 4 + h) * 256 + c) * 128 + db) = vv;
        }
    } else {
        #pragma unroll
        for (int i = 0; i < 8; ++i) {
            int u = i * 256 + t;
            int rowr = u >> 4;                   // 0..127 (2 heads x 64 d)
            int hl = rowr >> 6, d = rowr & 63;
            int cb2 = (u & 15) * 16;
            int c2 = cb2 ^ ((d & 7) << 4);       // un-swizzle -> logical c byte
            uint4 vv = *reinterpret_cast<const uint4*>((char*)T + u * 16);
            *reinterpret_cast<uint4*>(
                (char*)Vt + (size_t)((n * 4 + h0 + hl) * 64 + d) * 512 + (bm & 1) * 256 + c2) = vv;
        }
    }
}

// ---------------------------------------------------------------------------
// Attention v3. One block per (n,h); 4 independent waves; K AND V in LDS
// (XOR-swizzled, conflict-free). In-register softmax (structure verified in
// round 2). O stored pre-swizzled for gemm3<1> (Otr read-XOR cancels).
// ---------------------------------------------------------------------------
__global__ __launch_bounds__(256) void attn3(
    const unsigned short* __restrict__ Q,
    const unsigned short* __restrict__ K,
    const unsigned short* __restrict__ V,
    unsigned short* __restrict__ O)
{
    __shared__ __align__(16) char KsB[32768];     // [256 key][128B] swizzled
    __shared__ __align__(16) char VsB[32768];     // [64 d][512B] swizzled
    __shared__ __align__(16) char OtrB[4][2048];  // per-wave transpose

    const int nh = blockIdx.x;
    const int n = nh >> 2, h = nh & 3;
    const int t = threadIdx.x, w = t >> 6, lane = t & 63;
    const int lr = lane & 15, lk = lane >> 4;

    const unsigned short* Qg = Q + (size_t)nh * 16384;
    const char* Kg = (const char*)K + (size_t)nh * 32768;
    const char* Vg = (const char*)V + (size_t)nh * 32768;

    #pragma unroll
    for (int i = 0; i < 8; ++i) {                 // stage K
        int u = i * 256 + t;
        int row = u >> 3, cb = (u & 7) * 16;
        uint4 val = *reinterpret_cast<const uint4*>(Kg + u * 16);
        *reinterpret_cast<uint4*>(KsB + row * 128 + (cb ^ ((row & 7) << 4))) = val;
    }
    #pragma unroll
    for (int i = 0; i < 8; ++i) {                 // stage V
        int u = i * 256 + t;
        int row = u >> 5, cb = (u & 31) * 16;
        uint4 val = *reinterpret_cast<const uint4*>(Vg + u * 16);
        *reinterpret_cast<uint4*>(VsB + row * 512 + (cb ^ ((row & 7) << 4))) = val;
    }
    __syncthreads();

    const float sc = 0.125f * 1.44269504f;   // HD^-0.5 * log2(e)

    for (int it = 0; it < 4; ++it) {
        const int qt = w * 4 + it;

        s16x8 bq0 = *reinterpret_cast<const s16x8*>(Qg + (qt * 16 + lr) * 64 + lk * 8);
        s16x8 bq1 = *reinterpret_cast<const s16x8*>(Qg + (qt * 16 + lr) * 64 + 32 + lk * 8);

        // S^T: lane holds S[key = 16*kt + 4*lk + j][q = qt*16+lr]
        f32x4 s[16];
        #pragma unroll
        for (int kt = 0; kt < 16; ++kt) {
            const int rb = (kt * 16 + lr) * 128;
            const int swz = (lr & 7) << 4;
            s16x8 a0 = *reinterpret_cast<const s16x8*>(KsB + rb + ((lk * 16) ^ swz));
            s16x8 a1 = *reinterpret_cast<const s16x8*>(KsB + rb + ((64 + lk * 16) ^ swz));
            f32x4 z = { 0.f, 0.f, 0.f, 0.f };
            z = __builtin_amdgcn_mfma_f32_16x16x32_bf16(a0, bq0, z, 0, 0, 0);
            z = __builtin_amdgcn_mfma_f32_16x16x32_bf16(a1, bq1, z, 0, 0, 0);
            s[kt] = z;
        }

        // in-register softmax across 256 keys
        float m = s[0][0];
        #pragma unroll
        for (int kt = 0; kt < 16; ++kt)
            #pragma unroll
            for (int j = 0; j < 4; ++j) m = fmaxf(m, s[kt][j]);
        m = fmaxf(m, __shfl_xor(m, 16));
        m = fmaxf(m, __shfl_xor(m, 32));
        float l = 0.f;
        #pragma unroll
        for (int kt = 0; kt < 16; ++kt)
            #pragma unroll
            for (int j = 0; j < 4; ++j) {
                float p = exp2f((s[kt][j] - m) * sc);
                s[kt][j] = p;
                l += p;
            }
        l += __shfl_xor(l, 16);
        l += __shfl_xor(l, 32);

        // O^T = V^T @ P^T, V from LDS (swizzled), permuted-key bijection
        f32x4 oacc[4] = {};
        #pragma unroll
        for (int kb = 0; kb < 8; ++kb) {
            uint4 pf = { pack2(s[2 * kb][0],     s[2 * kb][1]),
                         pack2(s[2 * kb][2],     s[2 * kb][3]),
                         pack2(s[2 * kb + 1][0], s[2 * kb + 1][1]),
                         pack2(s[2 * kb + 1][2], s[2 * kb + 1][3]) };
            s16x8 bp = u4cast(pf);
            #pragma unroll
            for (int dt = 0; dt < 4; ++dt) {
                const int row = dt * 16 + lr;
                const char* vb = VsB + row * 512;
                const int swz = (lr & 7) << 4;
                uint2 v0 = *reinterpret_cast<const uint2*>(vb + ((kb * 64 + lk * 8) ^ swz));
                uint2 v1 = *reinterpret_cast<const uint2*>(vb + ((kb * 64 + lk * 8 + 32) ^ swz));
                uint4 uu = { v0.x, v0.y, v1.x, v1.y };
                oacc[dt] = __builtin_amdgcn_mfma_f32_16x16x32_bf16(u4cast(uu), bp, oacc[dt], 0, 0, 0);
            }
        }

        // normalize; transpose via per-wave LDS; store PRE-SWIZZLED for gemm2
        const float rl = 1.0f / l;
        char* ob = OtrB[w];
        #pragma unroll
        for (int dt = 0; dt < 4; ++dt) {
            unsigned int w0 = pack2(oacc[dt][0] * rl, oacc[dt][1] * rl);
            unsigned int w1 = pack2(oacc[dt][2] * rl, oacc[dt][3] * rl);
            int cb0 = dt * 32 + lk * 8;
            int swz = (lr & 7) << 4;
            *reinterpret_cast<unsigned int*>(ob + lr * 128 + (cb0 ^ swz)) = w0;
            *reinterpret_cast<unsigned int*>(ob + lr * 128 + ((cb0 + 4) ^ swz)) = w1;
        }
        #pragma unroll
        for (int pp = 0; pp < 2; ++pp) {
            int qrow = lane >> 2;
            int cbX = (lane & 3) * 32 + pp * 16;   // PHYS offset (swizzles cancel)
            uint4 vv = *reinterpret_cast<const uint4*>(ob + qrow * 128 + cbX);
            *reinterpret_cast<uint4*>(
                (char*)O + (size_t)(n * 256 + qt * 16 + qrow) * 512 + h * 128 + cbX) = vv;
        }
    }
}

// ---------------------------------------------------------------------------
extern "C" void kernel_launch(void* const* d_in, const int* in_sizes, int n_in,
                              void* d_out, int out_size, void* d_ws, size_t ws_size,
                              hipStream_t stream) {
    const float* x     = (const float*)d_in[0];
    const float* w_in  = (const float*)d_in[1];
    const float* b_in  = (const float*)d_in[2];
    const float* w_out = (const float*)d_in[3];
    const float* b_out = (const float*)d_in[4];

    char* ws = (char*)d_ws;
    unsigned short* tO = (unsigned short*)(ws);               // t, later O
    unsigned short* Qw = (unsigned short*)(ws + WS_SEG);
    unsigned short* Kw = (unsigned short*)(ws + 2 * WS_SEG);
    unsigned short* Vw = (unsigned short*)(ws + 3 * WS_SEG);

    // bf16 w_in in d_out tail (read by gemm1, overwritten later by gemm2)
    unsigned short* WbIn = (unsigned short*)((float*)d_out + out_size - 98304);

    convw_swz<<<192, 256, 0, stream>>>(w_in, WbIn);
    gather_swz<<<32768, 256, 0, stream>>>(x, tO);

    gemm3<0><<<dim3(6, 1024), 256, 0, stream>>>(tO, WbIn, b_in, Qw, Kw, Vw, nullptr);

    attn3<<<2048, 256, 0, stream>>>(Qw, Kw, Vw, tO);          // O overwrites t

    unsigned short* WbOut = Kw;                               // K dead after attn
    convw_swz<<<64, 256, 0, stream>>>(w_out, WbOut);

    gemm3<1><<<dim3(2, 1024), 256, 0, stream>>>(tO, WbOut, b_out,
                                                nullptr, nullptr, nullptr, (float*)d_out);
}